// Round 6
// baseline (322.646 us; speedup 1.0000x reference)
//
#include <hip/hip_runtime.h>

// Depthwise 7x7 cross-correlation, same padding.
// x:    [8, 256, 64, 64]   fp32
// tmpl: [8, 8, 256, 7, 7]  fp32  (nt, bs, nc, ht, wt)
// out:  [8, 8, 256, 64, 64] fp32
//
// One block per (b,c) plane; x staged into LDS once, reused by all 8 templates.
// Structure: 8x4 per-thread output tile, 2 templates concurrently (half-block
// each, wave-uniform t), 4 rounds; 49 taps in SGPRs via readfirstlane.
//
// v7 = v6 + register ping-pong on the row window (T14 issue-early/consume-
// late): each 2-row region issues the NEXT pair's 6 ds_read_b128, fences with
// sched_barrier(0), then runs ~224 FMAs on the PREVIOUS pair's data -- the
// ~120-cyc LDS latency is fully covered instead of exposed at each region
// start. Tap loads issue before the prologue reads + acc init so their
// latency is partially hidden too.
// History: (256,4)/(256,2) caps -> spill cliff (1365/441/385us); uncapped no
// fences -> ~160 VGPR, 2 waves/SIMD, ~155us; v6 fences-only -> ~118us.
// Live set here: acc 32 + 2x24 window + addr ~= 100 VGPR -> no cap, no spill,
// >=3 waves/SIMD. Bank conflicts measured ~1% at LSTR=72 -- no swizzle.

#define NT 8
#define BS 8
#define NC 256
#define HW 64
#define PLANE (HW * HW)          // 4096
#define LROWS 70
#define LSTR  72                 // row stride in floats; 288 B (16B mult)

__global__ __launch_bounds__(256) void dwxcorr_kernel(
    const float* __restrict__ x,
    const float* __restrict__ tm,
    float* __restrict__ out)
{
    __shared__ __align__(16) float xpl[LROWS * LSTR];     // 20160 B

    const int bc  = blockIdx.x;          // b*256 + c, 0..2047
    const int tid = threadIdx.x;

    // ---- zero ONLY the pad cells: 236 float4 total, <=1 per thread ----
    if (tid < 236) {
        int off;
        if (tid < 54)       off = tid * 4;                        // rows 0..2
        else if (tid < 108) off = 67 * LSTR + (tid - 54) * 4;     // rows 67..69
        else if (tid < 172) off = (3 + (tid - 108)) * LSTR;       // left pad
        else                off = (3 + (tid - 172)) * LSTR + 68;  // right pad
        *(float4*)&xpl[off] = make_float4(0.f, 0.f, 0.f, 0.f);
    }

    // ---- stage x interior: 1024 float4 loads, coalesced (disjoint from pads)
    const float* xp = x + bc * PLANE;
    for (int i = tid; i < PLANE / 4; i += 256) {
        float4 v = ((const float4*)xp)[i];
        int row = i >> 4;              // 16 float4 per 64-wide row
        int c4  = (i & 15) << 2;
        *(float4*)&xpl[(row + 3) * LSTR + 4 + c4] = v;
    }
    __syncthreads();

    // ---- compute geometry: 128 threads cover the plane per template ----
    const int half = __builtin_amdgcn_readfirstlane(tid >> 7);
    const int lid  = tid & 127;
    const int tx   = lid & 15;           // col group: cols 4*tx..4*tx+3
    const int ty   = lid >> 4;           // row group: rows 8*ty..8*ty+7
    const int col0 = tx << 2;
    const int row0 = ty << 3;

    for (int rnd = 0; rnd < 4; ++rnd) {
        const int t = (rnd << 1) + half;

        // ---- taps -> SGPRs: uniform address, readfirstlane the bits.
        // Issued FIRST so prologue reads + acc init hide some latency.
        const float* wg = tm + ((size_t)t * (BS * NC) + bc) * 49;
        float w[49];
        #pragma unroll
        for (int k = 0; k < 49; ++k) {
            union { float f; int i; } u;
            u.f = wg[k];
            u.i = __builtin_amdgcn_readfirstlane(u.i);
            w[k] = u.f;
        }

        // ---- row-window ping-pong buffers: 2 pairs x 2 rows x 12 floats ----
        float buf[2][2][12];

        // prologue: load pair 0 (LDS relative rows 0,1)
        #pragma unroll
        for (int q = 0; q < 2; ++q) {
            const float* rp = &xpl[(row0 + q) * LSTR + col0];
            float4 a = *(const float4*)(rp);
            float4 b = *(const float4*)(rp + 4);
            float4 c = *(const float4*)(rp + 8);
            buf[0][q][0] = a.x; buf[0][q][1]  = a.y; buf[0][q][2]  = a.z; buf[0][q][3]  = a.w;
            buf[0][q][4] = b.x; buf[0][q][5]  = b.y; buf[0][q][6]  = b.z; buf[0][q][7]  = b.w;
            buf[0][q][8] = c.x; buf[0][q][9]  = c.y; buf[0][q][10] = c.z; buf[0][q][11] = c.w;
        }
        __builtin_amdgcn_sched_barrier(0);

        float acc[8][4];
        #pragma unroll
        for (int r = 0; r < 8; ++r)
            #pragma unroll
            for (int j = 0; j < 4; ++j) acc[r][j] = 0.0f;

        // ---- 7 regions of 2 rows; region reg computes rows 2reg,2reg+1 ----
        #pragma unroll
        for (int reg = 0; reg < 7; ++reg) {
            const int cur = reg & 1, nxt = cur ^ 1;

            // issue NEXT pair's reads (rows 2reg+2, 2reg+3) before computing
            if (reg < 6) {
                #pragma unroll
                for (int q = 0; q < 2; ++q) {
                    const float* rp = &xpl[(row0 + 2 * reg + 2 + q) * LSTR + col0];
                    float4 a = *(const float4*)(rp);
                    float4 b = *(const float4*)(rp + 4);
                    float4 c = *(const float4*)(rp + 8);
                    buf[nxt][q][0] = a.x; buf[nxt][q][1]  = a.y; buf[nxt][q][2]  = a.z; buf[nxt][q][3]  = a.w;
                    buf[nxt][q][4] = b.x; buf[nxt][q][5]  = b.y; buf[nxt][q][6]  = b.z; buf[nxt][q][7]  = b.w;
                    buf[nxt][q][8] = c.x; buf[nxt][q][9]  = c.y; buf[nxt][q][10] = c.z; buf[nxt][q][11] = c.w;
                }
            }
            __builtin_amdgcn_sched_barrier(0);

            // FMAs on CURRENT pair (loaded a region ago; latency covered)
            #pragma unroll
            for (int q = 0; q < 2; ++q) {
                const int ir = 2 * reg + q;            // unroll-constant
                #pragma unroll
                for (int r = 0; r < 8; ++r) {
                    const int ky = ir - r;             // compile-time
                    if (ky >= 0 && ky < 7) {
                        #pragma unroll
                        for (int kx = 0; kx < 7; ++kx) {
                            const float tv = w[ky * 7 + kx];   // SGPR operand
                            #pragma unroll
                            for (int j = 0; j < 4; ++j)
                                acc[r][j] = fmaf(buf[cur][q][j + kx + 1], tv, acc[r][j]);
                        }
                    }
                }
            }
            __builtin_amdgcn_sched_barrier(0);
        }

        // ---- store 8 rows x float4, coalesced across tx (256B runs) ----
        float* op = out + (size_t)(t * (BS * NC) + bc) * PLANE + row0 * HW + col0;
        #pragma unroll
        for (int r = 0; r < 8; ++r) {
            float4 v = make_float4(acc[r][0], acc[r][1], acc[r][2], acc[r][3]);
            *(float4*)(op + r * HW) = v;
        }
    }
}

extern "C" void kernel_launch(void* const* d_in, const int* in_sizes, int n_in,
                              void* d_out, int out_size, void* d_ws, size_t ws_size,
                              hipStream_t stream) {
    const float* x  = (const float*)d_in[0];
    const float* tm = (const float*)d_in[1];
    float* out = (float*)d_out;
    dwxcorr_kernel<<<BS * NC, 256, 0, stream>>>(x, tm, out);
}

// Round 7
// 320.561 us; speedup vs baseline: 1.0065x; 1.0065x over previous
//
#include <hip/hip_runtime.h>

// Depthwise 7x7 cross-correlation, same padding.
// x:    [8, 256, 64, 64]   fp32
// tmpl: [8, 8, 256, 7, 7]  fp32  (nt, bs, nc, ht, wt)
// out:  [8, 8, 256, 64, 64] fp32
//
// One block per (b,c) plane; x staged into LDS once, reused by all 8 templates.
// Structure: 8x4 per-thread output tile, 2 templates concurrently (half-block
// each, wave-uniform t), 4 rounds; row-window register ping-pong + sched
// fences (v6/v7) bound the live set by construction.
//
// v8 key changes:
// 1) Taps via ONE lane-indexed global load + 49 v_readlane -> SGPRs.
//    The old path (49 uniform loads + readfirstlane on DATA) created a
//    49-VGPR transient burst each round -- that burst is what pegged the
//    128 cap and spilled in v3/v5. Now: 1 transient VGPR, 1 load/round.
// 2) __launch_bounds__(256,2) (empirical cap = 128 VGPR). Occupancy steps
//    halve at VGPR=64/128/256 (no 3-wave step), so v6/v7's uncapped ~130-190
//    VGPR ran at 2 waves/SIMD -- the stall holes that capped VALUBusy ~40%.
//    Steady live set now ~= acc 32 + window 48 + addr 15 ~= 95-100 -> the
//    cap is safe and buys 4 waves/SIMD (LDS 20.5KB x 4 blocks = 82KB ok).
// History: caps without bounded live set -> spill cliff (1365/441/385us);
// uncapped+fences v6 ~118us; +ping-pong v7 neutral (latency already hidden).
// Bank conflicts ~1% at LSTR=72 -- no swizzle needed.

#define NT 8
#define BS 8
#define NC 256
#define HW 64
#define PLANE (HW * HW)          // 4096
#define LROWS 70
#define LSTR  72                 // row stride in floats; 288 B (16B mult)

__global__ __launch_bounds__(256, 2) void dwxcorr_kernel(
    const float* __restrict__ x,
    const float* __restrict__ tm,
    float* __restrict__ out)
{
    __shared__ __align__(16) float xpl[LROWS * LSTR];     // 20160 B

    const int bc  = blockIdx.x;          // b*256 + c, 0..2047
    const int tid = threadIdx.x;

    // ---- zero ONLY the pad cells: 236 float4 total, <=1 per thread ----
    if (tid < 236) {
        int off;
        if (tid < 54)       off = tid * 4;                        // rows 0..2
        else if (tid < 108) off = 67 * LSTR + (tid - 54) * 4;     // rows 67..69
        else if (tid < 172) off = (3 + (tid - 108)) * LSTR;       // left pad
        else                off = (3 + (tid - 172)) * LSTR + 68;  // right pad
        *(float4*)&xpl[off] = make_float4(0.f, 0.f, 0.f, 0.f);
    }

    // ---- stage x interior: 1024 float4 loads, coalesced (disjoint from pads)
    const float* xp = x + bc * PLANE;
    for (int i = tid; i < PLANE / 4; i += 256) {
        float4 v = ((const float4*)xp)[i];
        int row = i >> 4;              // 16 float4 per 64-wide row
        int c4  = (i & 15) << 2;
        *(float4*)&xpl[(row + 3) * LSTR + 4 + c4] = v;
    }
    __syncthreads();

    // ---- compute geometry: 128 threads cover the plane per template ----
    const int half = __builtin_amdgcn_readfirstlane(tid >> 7);
    const int lane = tid & 63;
    const int lid  = tid & 127;
    const int tx   = lid & 15;           // col group: cols 4*tx..4*tx+3
    const int ty   = lid >> 4;           // row group: rows 8*ty..8*ty+7
    const int col0 = tx << 2;
    const int row0 = ty << 3;
    const int klane = lane < 49 ? lane : 48;   // clamp to stay in-bounds

    for (int rnd = 0; rnd < 4; ++rnd) {
        const int t = (rnd << 1) + half;

        // ---- taps: ONE lane-indexed load (lanes 0..48 hold tap[lane]),
        // then v_readlane each tap into an SGPR. 1 transient VGPR total.
        // tm layout: t*(8*256*49) + (b*256+c)*49 + k
        const float* wg = tm + ((size_t)t * (BS * NC) + bc) * 49;
        union { float f; int i; } tv;
        tv.f = wg[klane];

        // ---- row-window ping-pong buffers: 2 pairs x 2 rows x 12 floats ----
        float buf[2][2][12];

        // prologue: load pair 0 (LDS relative rows 0,1) while tap load flies
        #pragma unroll
        for (int q = 0; q < 2; ++q) {
            const float* rp = &xpl[(row0 + q) * LSTR + col0];
            float4 a = *(const float4*)(rp);
            float4 b = *(const float4*)(rp + 4);
            float4 c = *(const float4*)(rp + 8);
            buf[0][q][0] = a.x; buf[0][q][1]  = a.y; buf[0][q][2]  = a.z; buf[0][q][3]  = a.w;
            buf[0][q][4] = b.x; buf[0][q][5]  = b.y; buf[0][q][6]  = b.z; buf[0][q][7]  = b.w;
            buf[0][q][8] = c.x; buf[0][q][9]  = c.y; buf[0][q][10] = c.z; buf[0][q][11] = c.w;
        }

        float acc[8][4];
        #pragma unroll
        for (int r = 0; r < 8; ++r)
            #pragma unroll
            for (int j = 0; j < 4; ++j) acc[r][j] = 0.0f;

        // pull taps into SGPRs (uniform values; FMA takes 1 SGPR operand)
        float w[49];
        #pragma unroll
        for (int k = 0; k < 49; ++k) {
            union { float f; int i; } u;
            u.i = __builtin_amdgcn_readlane(tv.i, k);
            w[k] = u.f;
        }
        __builtin_amdgcn_sched_barrier(0);

        // ---- 7 regions of 2 rows; region reg computes rows 2reg,2reg+1 ----
        #pragma unroll
        for (int reg = 0; reg < 7; ++reg) {
            const int cur = reg & 1, nxt = cur ^ 1;

            // issue NEXT pair's reads (rows 2reg+2, 2reg+3) before computing
            if (reg < 6) {
                #pragma unroll
                for (int q = 0; q < 2; ++q) {
                    const float* rp = &xpl[(row0 + 2 * reg + 2 + q) * LSTR + col0];
                    float4 a = *(const float4*)(rp);
                    float4 b = *(const float4*)(rp + 4);
                    float4 c = *(const float4*)(rp + 8);
                    buf[nxt][q][0] = a.x; buf[nxt][q][1]  = a.y; buf[nxt][q][2]  = a.z; buf[nxt][q][3]  = a.w;
                    buf[nxt][q][4] = b.x; buf[nxt][q][5]  = b.y; buf[nxt][q][6]  = b.z; buf[nxt][q][7]  = b.w;
                    buf[nxt][q][8] = c.x; buf[nxt][q][9]  = c.y; buf[nxt][q][10] = c.z; buf[nxt][q][11] = c.w;
                }
            }
            __builtin_amdgcn_sched_barrier(0);

            // FMAs on CURRENT pair (loaded a region ago; latency covered)
            #pragma unroll
            for (int q = 0; q < 2; ++q) {
                const int ir = 2 * reg + q;            // unroll-constant
                #pragma unroll
                for (int r = 0; r < 8; ++r) {
                    const int ky = ir - r;             // compile-time
                    if (ky >= 0 && ky < 7) {
                        #pragma unroll
                        for (int kx = 0; kx < 7; ++kx) {
                            const float tvv = w[ky * 7 + kx];   // SGPR operand
                            #pragma unroll
                            for (int j = 0; j < 4; ++j)
                                acc[r][j] = fmaf(buf[cur][q][j + kx + 1], tvv, acc[r][j]);
                        }
                    }
                }
            }
            __builtin_amdgcn_sched_barrier(0);
        }

        // ---- store 8 rows x float4, coalesced across tx (256B runs) ----
        float* op = out + (size_t)(t * (BS * NC) + bc) * PLANE + row0 * HW + col0;
        #pragma unroll
        for (int r = 0; r < 8; ++r) {
            float4 v = make_float4(acc[r][0], acc[r][1], acc[r][2], acc[r][3]);
            *(float4*)(op + r * HW) = v;
        }
    }
}

extern "C" void kernel_launch(void* const* d_in, const int* in_sizes, int n_in,
                              void* d_out, int out_size, void* d_ws, size_t ws_size,
                              hipStream_t stream) {
    const float* x  = (const float*)d_in[0];
    const float* tm = (const float*)d_in[1];
    float* out = (float*)d_out;
    dwxcorr_kernel<<<BS * NC, 256, 0, stream>>>(x, tm, out);
}